// Round 1
// baseline (194.214 us; speedup 1.0000x reference)
//
#include <hip/hip_runtime.h>
#include <hip/hip_bf16.h>

// BEV bilinear feature extraction.
// feats: (B=4, C=256, H=188, W=188) f32
// centers: (B=4, N=500, 3) f32
// out: (B, N, C) f32
//
// One block per (b, n) point; threadIdx.x = channel. Each thread gathers
// the 4 bilinear corners for its channel (lane-stride H*W*4 B — inherent
// gather given the (B,C,H,W) layout) and writes one coalesced output.

constexpr int B = 4;
constexpr int C = 256;
constexpr int H = 188;
constexpr int W = 188;
constexpr int N = 500;

__global__ __launch_bounds__(256) void bev_extract_kernel(
    const float* __restrict__ feats,
    const float* __restrict__ centers,
    float* __restrict__ out)
{
    const int pt = blockIdx.x;          // 0 .. B*N-1
    const int c  = threadIdx.x;         // 0 .. 255
    const int b  = pt / N;
    const int n  = pt - b * N;

    // All threads redundantly compute the point's coords (cheap, uniform).
    const float cx = centers[(b * N + n) * 3 + 0];
    const float cy = centers[(b * N + n) * 3 + 1];

    // Match reference numerics: (c - PC_START) / VOXEL / OUT_STRIDE
    const float x = (cx - (-75.2f)) / 0.1f / 8.0f;
    const float y = (cy - (-75.2f)) / 0.1f / 8.0f;

    // Clamp BEFORE weight computation (torch/reference semantics).
    const int xf = (int)floorf(x);
    const int yf = (int)floorf(y);
    const int x0 = min(max(xf,     0), W - 1);
    const int x1 = min(max(xf + 1, 0), W - 1);
    const int y0 = min(max(yf,     0), H - 1);
    const int y1 = min(max(yf + 1, 0), H - 1);

    const float x0f = (float)x0, x1f = (float)x1;
    const float y0f = (float)y0, y1f = (float)y1;
    const float wa = (x1f - x) * (y1f - y);
    const float wb = (x1f - x) * (y  - y0f);
    const float wc = (x  - x0f) * (y1f - y);
    const float wd = (x  - x0f) * (y  - y0f);

    const float* base = feats + (size_t)(b * C + c) * (H * W);
    const float Ia = base[y0 * W + x0];
    const float Ib = base[y1 * W + x0];
    const float Ic = base[y0 * W + x1];
    const float Id = base[y1 * W + x1];

    out[(size_t)pt * C + c] = Ia * wa + Ib * wb + Ic * wc + Id * wd;
}

extern "C" void kernel_launch(void* const* d_in, const int* in_sizes, int n_in,
                              void* d_out, int out_size, void* d_ws, size_t ws_size,
                              hipStream_t stream)
{
    const float* feats   = (const float*)d_in[0];  // (B, C, H, W)
    const float* centers = (const float*)d_in[1];  // (B, N, 3)
    float* out = (float*)d_out;                    // (B, N, C)

    dim3 grid(B * N);
    dim3 block(C);
    bev_extract_kernel<<<grid, block, 0, stream>>>(feats, centers, out);
}